// Round 1
// 239.529 us; speedup vs baseline: 1.0634x; 1.0634x over previous
//
#include <hip/hip_runtime.h>

#define H 128
#define LSTRIDE 136   // LDS row stride in bf16 elems: 272B, 16B-aligned, 2-way bank (free)
#define PSTR 132      // pool stride in floats: rl*132 -> bank offset rl*4, 2-way (free)
typedef unsigned int uint32;
typedef unsigned short ushort16;
typedef __attribute__((ext_vector_type(8))) short bf16x8;
typedef __attribute__((ext_vector_type(4))) float f32x4;

static __device__ __forceinline__ ushort16 f2bf(float f){
  uint32 u = __float_as_uint(f);
  uint32 r = (u + 0x7fff + ((u >> 16) & 1)) >> 16;   // RNE bf16 (finite values)
  return (ushort16)r;
}
static __device__ __forceinline__ float bflo(uint32 u){ return __uint_as_float(u << 16); }
static __device__ __forceinline__ float bfhi(uint32 u){ return __uint_as_float(u & 0xffff0000u); }

// fused setup: deg=0, gsum=0, gb[0..G]; zero sentinel rows (y0[N], ybufA[N], ybufB[N]);
// last 16 blocks prep W2/W3 into MFMA B-frag bf16
__global__ __launch_bounds__(256) void k_setup(int* __restrict__ deg, float* __restrict__ gsum,
                                               const int* __restrict__ batch, int n, int G,
                                               int* __restrict__ gb, int SB,
                                               const float* __restrict__ W2, const float* __restrict__ W3,
                                               ushort16* __restrict__ wp2, ushort16* __restrict__ wp3,
                                               float4* __restrict__ y0,
                                               unsigned short* __restrict__ ybA,
                                               unsigned short* __restrict__ ybB){
  int b = blockIdx.x;
  if (b < SB){
    int i = b*256 + threadIdx.x;
    if (i < n) deg[i] = 0;
    if (i < G*H) gsum[i] = 0.f;
    if (i < H){ ybA[(size_t)n*H + i] = 0; ybB[(size_t)n*H + i] = 0; }
    if (i == 0) y0[n] = make_float4(0.f, 0.f, 0.f, 0.f);
    if (i <= G){
      int lo = 0, hi = n;
      while (lo < hi){ int m = (lo + hi) >> 1; if (batch[m] < i) lo = m + 1; else hi = m; }
      gb[i] = lo;
    }
  } else {
    int gid = (b - SB)*256 + threadIdx.x;   // 0..4095
    const float* W = (gid < 2048) ? W2 : W3;
    ushort16* wp   = (gid < 2048) ? wp2 : wp3;
    int tid = gid & 2047;
    int frag = tid >> 6, lane = tid & 63;
    int kt = frag >> 3, ct = frag & 7;
    int m = lane & 15, quad = lane >> 4;
    const float* wrow = &W[(kt*32 + quad*8)*H + ct*16 + m];
    ushort16 vals[8];
    #pragma unroll
    for (int j = 0; j < 8; j++) vals[j] = f2bf(wrow[j*H]);
    uint4 o;
    o.x = (uint32)vals[0] | ((uint32)vals[1] << 16);
    o.y = (uint32)vals[2] | ((uint32)vals[3] << 16);
    o.z = (uint32)vals[4] | ((uint32)vals[5] << 16);
    o.w = (uint32)vals[6] | ((uint32)vals[7] << 16);
    *(uint4*)&wp[(size_t)tid*8] = o;
  }
}

// rank[e] = position of edge e within its dst bucket (ushort: max deg << 65536)
__global__ __launch_bounds__(256) void k_count_rank(const int* __restrict__ dst, int E,
                                                    int* __restrict__ deg, unsigned short* __restrict__ rank){
  int i = blockIdx.x*256 + threadIdx.x;
  if (i < E) rank[i] = (unsigned short)atomicAdd(&deg[dst[i]], 1);
}

// ---- scan of padded counts round8(deg+1) -> block-local offsets, block totals to bsum, dinv,
//      fused prescale: y0[i] = dinv[i] * pos[i] ----
__global__ __launch_bounds__(256) void k_scan1(const int* __restrict__ deg, int n,
      int* __restrict__ offsets, int* __restrict__ bsum, float* __restrict__ dinv,
      const float* __restrict__ pos, float4* __restrict__ y0){
  __shared__ int sh[256];
  int b = blockIdx.x, t = threadIdx.x;
  int base = b*1024 + t*4;
  bool i0 = base+0 < n, i1 = base+1 < n, i2 = base+2 < n, i3 = base+3 < n;
  int d0=0,d1=0,d2=0,d3=0;
  if (i3){ int4 v = *(const int4*)&deg[base]; d0=v.x; d1=v.y; d2=v.z; d3=v.w; }
  else {
    if (i0) d0 = deg[base+0];
    if (i1) d1 = deg[base+1];
    if (i2) d2 = deg[base+2];
  }
  // padded entry count: (deg + 1 self-loop) rounded up to multiple of 8
  int e0 = i0? ((d0+8)&~7):0, e1 = i1? ((d1+8)&~7):0, e2 = i2? ((d2+8)&~7):0, e3 = i3? ((d3+8)&~7):0;
  sh[t] = e0+e1+e2+e3;
  __syncthreads();
  for (int off=1; off<256; off<<=1){
    int v = sh[t];
    int add = (t>=off)? sh[t-off] : 0;
    __syncthreads();
    sh[t] = v+add;
    __syncthreads();
  }
  int o0 = (t==0)?0:sh[t-1];
  int o1 = o0+e0, o2 = o1+e1, o3 = o2+e2;
  float dv0 = rsqrtf((float)(d0+1)), dv1 = rsqrtf((float)(d1+1));
  float dv2 = rsqrtf((float)(d2+1)), dv3 = rsqrtf((float)(d3+1));
  if (i0){ offsets[base+0]=o0; dinv[base+0]=dv0; }
  if (i1){ offsets[base+1]=o1; dinv[base+1]=dv1; }
  if (i2){ offsets[base+2]=o2; dinv[base+2]=dv2; }
  if (i3){ offsets[base+3]=o3; dinv[base+3]=dv3; }
  if (i3){
    float4 p0 = *(const float4*)&pos[3*base];      // x0 y0 z0 x1
    float4 p1 = *(const float4*)&pos[3*base+4];    // y1 z1 x2 y2
    float4 p2 = *(const float4*)&pos[3*base+8];    // z2 x3 y3 z3
    y0[base+0] = make_float4(p0.x*dv0, p0.y*dv0, p0.z*dv0, 0.f);
    y0[base+1] = make_float4(p0.w*dv1, p1.x*dv1, p1.y*dv1, 0.f);
    y0[base+2] = make_float4(p1.z*dv2, p1.w*dv2, p2.x*dv2, 0.f);
    y0[base+3] = make_float4(p2.y*dv3, p2.z*dv3, p2.w*dv3, 0.f);
  } else {
    if (i0) y0[base+0] = make_float4(pos[3*base+0]*dv0, pos[3*base+1]*dv0, pos[3*base+2]*dv0, 0.f);
    if (i1) y0[base+1] = make_float4(pos[3*base+3]*dv1, pos[3*base+4]*dv1, pos[3*base+5]*dv1, 0.f);
    if (i2) y0[base+2] = make_float4(pos[3*base+6]*dv2, pos[3*base+7]*dv2, pos[3*base+8]*dv2, 0.f);
  }
  if (t==255) bsum[b] = sh[255];
}

// add block prefix; prefix computed in-wave from bsum (requires B <= 64). Last block writes offsets[n].
__global__ __launch_bounds__(256) void k_scan3b(int* __restrict__ offsets, int n,
                                                const int* __restrict__ bsum, int B){
  __shared__ int sh[2];
  int b = blockIdx.x, t = threadIdx.x;
  if (t < 64){
    int v   = (t < B)? bsum[t] : 0;
    int pre = (t < b)? v : 0;
    int tot = v;
    for (int o=1; o<64; o<<=1){ pre += __shfl_xor(pre,o); tot += __shfl_xor(tot,o); }
    if (t == 0){ sh[0] = pre; sh[1] = tot; }
  }
  __syncthreads();
  int add = sh[0];
  int base = b*1024 + t*4;
  if (base+3 < n){
    int4 v = *(int4*)&offsets[base];
    v.x+=add; v.y+=add; v.z+=add; v.w+=add;
    *(int4*)&offsets[base] = v;
  } else {
    #pragma unroll
    for (int k=0;k<4;k++){ int i=base+k; if (i<n) offsets[i]+=add; }
  }
  if (b == B-1 && t == 255) offsets[n] = sh[1];
}

// atomic-free CSR fill (ushort payload): edge e -> slot offsets[dst]+1+rank[e]; self-loop at offsets[i];
// pad slots [offsets[i]+1+deg[i], offsets[i+1]) -> sentinel n (zero row)
__global__ __launch_bounds__(256) void k_fill2(const int* __restrict__ src, const int* __restrict__ dst,
            int E, int n, const int* __restrict__ offsets, const int* __restrict__ deg,
            const unsigned short* __restrict__ rank, unsigned short* __restrict__ csr_src){
  int i = blockIdx.x*256 + threadIdx.x;
  if (i < E){
    csr_src[offsets[dst[i]] + 1 + rank[i]] = (unsigned short)src[i];
  } else if (i < E + n){
    int j = i - E;
    int o = offsets[j];
    csr_src[o] = (unsigned short)j;
    int end = offsets[j+1];
    for (int s2 = o + 1 + deg[j]; s2 < end; s2++) csr_src[s2] = (unsigned short)n;
  }
}

// Fused layer 1: per node, a = dinv * sum_src y0[src] (3-wide gather), then
// y1[node,c] = bf16( dinv * relu(a . W1[:,c] + b1[c]) ) for all 128 cols (W1/b1 wave-uniform).
// CSR is 8-padded: branchless chunks, vectorized uint4 index loads.
__global__ __launch_bounds__(256) void k_layer1(const float4* __restrict__ y0, const int* __restrict__ offsets,
      const unsigned short* __restrict__ csr_src, const float* __restrict__ dinv,
      const float* __restrict__ W1, const float* __restrict__ b1,
      ushort16* __restrict__ y1, int n){
  int node = blockIdx.x*256 + threadIdx.x;
  if (node >= n) return;
  int lo = offsets[node], hi = offsets[node+1];
  float x=0.f, y=0.f, z=0.f;
  for (int e = lo; e < hi; e += 8){
    uint4 iv = *(const uint4*)&csr_src[e];
    int s0 = iv.x & 0xffff, s1 = iv.x >> 16;
    int s2 = iv.y & 0xffff, s3 = iv.y >> 16;
    int s4 = iv.z & 0xffff, s5 = iv.z >> 16;
    int s6 = iv.w & 0xffff, s7 = iv.w >> 16;
    float4 v0 = y0[s0], v1 = y0[s1], v2 = y0[s2], v3 = y0[s3];
    float4 v4 = y0[s4], v5 = y0[s5], v6 = y0[s6], v7 = y0[s7];
    x += ((v0.x+v1.x)+(v2.x+v3.x)) + ((v4.x+v5.x)+(v6.x+v7.x));
    y += ((v0.y+v1.y)+(v2.y+v3.y)) + ((v4.y+v5.y)+(v6.y+v7.y));
    z += ((v0.z+v1.z)+(v2.z+v3.z)) + ((v4.z+v5.z)+(v6.z+v7.z));
  }
  float dn = dinv[node];
  x *= dn; y *= dn; z *= dn;
  ushort16* rowp = &y1[(size_t)node*H];
  for (int c8 = 0; c8 < 16; c8++){
    float4 wa0 = *(const float4*)&W1[c8*8];
    float4 wa1 = *(const float4*)&W1[c8*8+4];
    float4 wb0 = *(const float4*)&W1[H + c8*8];
    float4 wb1 = *(const float4*)&W1[H + c8*8+4];
    float4 wc0 = *(const float4*)&W1[2*H + c8*8];
    float4 wc1 = *(const float4*)&W1[2*H + c8*8+4];
    float4 bb0 = *(const float4*)&b1[c8*8];
    float4 bb1 = *(const float4*)&b1[c8*8+4];
    float o0 = fmaxf(x*wa0.x + y*wb0.x + z*wc0.x + bb0.x, 0.f) * dn;
    float o1 = fmaxf(x*wa0.y + y*wb0.y + z*wc0.y + bb0.y, 0.f) * dn;
    float o2 = fmaxf(x*wa0.z + y*wb0.z + z*wc0.z + bb0.z, 0.f) * dn;
    float o3 = fmaxf(x*wa0.w + y*wb0.w + z*wc0.w + bb0.w, 0.f) * dn;
    float o4 = fmaxf(x*wa1.x + y*wb1.x + z*wc1.x + bb1.x, 0.f) * dn;
    float o5 = fmaxf(x*wa1.y + y*wb1.y + z*wc1.y + bb1.y, 0.f) * dn;
    float o6 = fmaxf(x*wa1.z + y*wb1.z + z*wc1.z + bb1.z, 0.f) * dn;
    float o7 = fmaxf(x*wa1.w + y*wb1.w + z*wc1.w + bb1.w, 0.f) * dn;
    uint4 o;
    o.x = (uint32)f2bf(o0) | ((uint32)f2bf(o1) << 16);
    o.y = (uint32)f2bf(o2) | ((uint32)f2bf(o3) << 16);
    o.z = (uint32)f2bf(o4) | ((uint32)f2bf(o5) << 16);
    o.w = (uint32)f2bf(o6) | ((uint32)f2bf(o7) << 16);
    *(uint4*)&rowp[c8*8] = o;
  }
}

// Fused aggregate + MFMA dense (full gather parallelism: 16 nodes/block, 16 lanes/node, one pass).
// CSR is 8-padded: branchless gather chunks with one uint4 index load per chunk.
// POOL=0: yout tile staged in LDS then coalesced 16B/lane bf16 stores (layer 2)
// POOL=1: relu(aW+b) -> LDS tile -> parallel segmented atomicAdd into gsum (layer 3 + pool numerator)
template<int POOL>
__global__ __launch_bounds__(256) void k_aggdense(const ushort16* __restrict__ y, const int* __restrict__ offsets,
      const unsigned short* __restrict__ csr_src, const float* __restrict__ dinv, const ushort16* __restrict__ wp,
      const float* __restrict__ bias,
      ushort16* __restrict__ yout, const int* __restrict__ batch, float* __restrict__ gsum, int n){
  __shared__ unsigned short As[16*LSTRIDE];          // 4352 B
  __shared__ float pool[POOL ? 16*PSTR : 1];         // 8448 B (POOL only)
  __shared__ unsigned short outs[POOL ? 1 : 16*PSTR];// 4224 B (non-POOL: staged bf16 out tile)
  __shared__ int sbatch[POOL ? 16 : 1];
  int tid = threadIdx.x;
  int node16 = blockIdx.x*16;
  int nl = tid >> 4;                 // local node 0..15
  int node = node16 + nl;
  int f8 = (tid & 15) * 8;

  if (POOL && tid < 16) sbatch[tid] = (node16 + tid < n) ? batch[node16 + tid] : -1;

  // ---- phase A: aggregate (branchless 8-wide chunks over padded CSR) ----
  float a0=0,a1=0,a2=0,a3=0,a4=0,a5=0,a6=0,a7=0;
  float dn = 0.f;
  #define ADDU(u) { a0+=bflo(u.x); a1+=bfhi(u.x); a2+=bflo(u.y); a3+=bfhi(u.y); \
                    a4+=bflo(u.z); a5+=bfhi(u.z); a6+=bflo(u.w); a7+=bfhi(u.w); }
  if (node < n){
    int lo = offsets[node], hi = offsets[node+1];
    dn = dinv[node];
    for (int e = lo; e < hi; e += 8){
      uint4 iv = *(const uint4*)&csr_src[e];
      int s0 = iv.x & 0xffff, s1 = iv.x >> 16;
      int s2 = iv.y & 0xffff, s3 = iv.y >> 16;
      int s4 = iv.z & 0xffff, s5 = iv.z >> 16;
      int s6 = iv.w & 0xffff, s7 = iv.w >> 16;
      uint4 u0 = *(const uint4*)&y[(size_t)s0*H + f8];
      uint4 u1 = *(const uint4*)&y[(size_t)s1*H + f8];
      uint4 u2 = *(const uint4*)&y[(size_t)s2*H + f8];
      uint4 u3 = *(const uint4*)&y[(size_t)s3*H + f8];
      uint4 u4 = *(const uint4*)&y[(size_t)s4*H + f8];
      uint4 u5 = *(const uint4*)&y[(size_t)s5*H + f8];
      uint4 u6 = *(const uint4*)&y[(size_t)s6*H + f8];
      uint4 u7 = *(const uint4*)&y[(size_t)s7*H + f8];
      ADDU(u0); ADDU(u1); ADDU(u2); ADDU(u3);
      ADDU(u4); ADDU(u5); ADDU(u6); ADDU(u7);
    }
  }
  #undef ADDU
  uint4 o;
  o.x = (uint32)f2bf(a0*dn) | ((uint32)f2bf(a1*dn) << 16);
  o.y = (uint32)f2bf(a2*dn) | ((uint32)f2bf(a3*dn) << 16);
  o.z = (uint32)f2bf(a4*dn) | ((uint32)f2bf(a5*dn) << 16);
  o.w = (uint32)f2bf(a6*dn) | ((uint32)f2bf(a7*dn) << 16);
  *(uint4*)&As[nl*LSTRIDE + f8] = o;
  __syncthreads();

  // ---- phase B: MFMA — wave w handles col-tiles {2w, 2w+1} over the 16 staged rows ----
  int wave = tid >> 6;
  int lane = tid & 63;
  int m = lane & 15, quad = lane >> 4;
  f32x4 acc0 = {0.f,0.f,0.f,0.f}, acc1 = {0.f,0.f,0.f,0.f};
  int ct0 = wave*2, ct1 = wave*2 + 1;
  #pragma unroll
  for (int kt = 0; kt < 4; kt++){
    bf16x8 af = *(const bf16x8*)&As[m*LSTRIDE + kt*32 + quad*8];
    bf16x8 b0 = *(const bf16x8*)&wp[(size_t)((kt*8+ct0)*64 + lane)*8];
    bf16x8 b1 = *(const bf16x8*)&wp[(size_t)((kt*8+ct1)*64 + lane)*8];
    acc0 = __builtin_amdgcn_mfma_f32_16x16x32_bf16(af, b0, acc0, 0, 0, 0);
    acc1 = __builtin_amdgcn_mfma_f32_16x16x32_bf16(af, b1, acc1, 0, 0, 0);
  }
  // C/D layout: col = ct*16 + m, row (in tile) = quad*4 + r
  #pragma unroll
  for (int j = 0; j < 2; j++){
    int ct = wave*2 + j;
    int col = ct*16 + m;
    float bv = bias[col];
    f32x4 ac = j ? acc1 : acc0;
    #pragma unroll
    for (int r = 0; r < 4; r++){
      int rl = quad*4 + r;
      int orow = node16 + rl;
      if (orow < n){
        float v = fmaxf(ac[r] + bv, 0.f);
        if (POOL) pool[rl*PSTR + col] = v;                            // one lane per (row,col)
        else      outs[rl*PSTR + col] = f2bf(v * dinv[orow]);
      }
    }
  }
  __syncthreads();
  if (POOL){
    // parallel segmented tail: 256 threads = 128 cols x 2 row-halves
    int col = tid & 127;
    int half = tid >> 7;
    float run = 0.f; int gprev = -1;
    for (int r = half*8; r < half*8 + 8; r++){
      int g = sbatch[r];
      if (g < 0) break;            // tail rows only
      if (g != gprev){
        if (gprev >= 0) atomicAdd(&gsum[gprev*H + col], run);
        run = 0.f; gprev = g;
      }
      run += pool[r*PSTR + col];
    }
    if (gprev >= 0) atomicAdd(&gsum[gprev*H + col], run);
  } else {
    // coalesced store: thread t writes row t>>4, 8 bf16 at (t&15)*8
    int row = tid >> 4;
    int orow = node16 + row;
    if (orow < n){
      const unsigned short* sp = &outs[row*PSTR + f8];
      uint4 v;
      v.x = (uint32)sp[0] | ((uint32)sp[1] << 16);
      v.y = (uint32)sp[2] | ((uint32)sp[3] << 16);
      v.z = (uint32)sp[4] | ((uint32)sp[5] << 16);
      v.w = (uint32)sp[6] | ((uint32)sp[7] << 16);
      *(uint4*)&yout[(size_t)orow*H + f8] = v;
    }
  }
}

// MLP head: relu((gsum/cnt) @ Wl1 + bl1) @ Wl2 + bl2
__global__ __launch_bounds__(64) void k_head(const float* __restrict__ gsum, const int* __restrict__ gb,
            const float* __restrict__ Wl1, const float* __restrict__ bl1,
            const float* __restrict__ Wl2, const float* __restrict__ bl2,
            float* __restrict__ out){
  int g = blockIdx.x;
  int t = threadIdx.x;
  __shared__ float gs[H];
  __shared__ float h1[64];
  float inv = 1.f / fmaxf((float)(gb[g+1] - gb[g]), 1.f);
  gs[t]      = gsum[g*H + t]      * inv;
  gs[64 + t] = gsum[g*H + 64 + t] * inv;
  __syncthreads();
  float acc = bl1[t];
  for (int k = 0; k < H; k++) acc += gs[k] * Wl1[k*64 + t];
  h1[t] = fmaxf(acc, 0.f);
  __syncthreads();
  if (t < 10){
    float o = bl2[t];
    for (int j = 0; j < 64; j++) o += h1[j] * Wl2[j*10 + t];
    out[g*10 + t] = o;
  }
}

extern "C" void kernel_launch(void* const* d_in, const int* in_sizes, int n_in,
                              void* d_out, int out_size, void* d_ws, size_t ws_size,
                              hipStream_t stream){
  const float* pos = (const float*)d_in[0];
  const int*  ei   = (const int*)d_in[1];
  const int*  batch= (const int*)d_in[2];
  const float* W1 = (const float*)d_in[3];
  const float* b1 = (const float*)d_in[4];
  const float* W2 = (const float*)d_in[5];
  const float* b2 = (const float*)d_in[6];
  const float* W3 = (const float*)d_in[7];
  const float* b3 = (const float*)d_in[8];
  const float* Wl1 = (const float*)d_in[9];
  const float* bl1 = (const float*)d_in[10];
  const float* Wl2 = (const float*)d_in[11];
  const float* bl2 = (const float*)d_in[12];
  float* out = (float*)d_out;

  int N = in_sizes[0] / 3;     // 50000 (< 65536 required for ushort CSR + sentinel)
  int E = in_sizes[1] / 2;     // 800000
  int G = out_size / 10;       // 64
  int B = (N + 1023) / 1024;   // 49, must be <= 64 for k_scan3b
  int SB = (N + 255) / 256;    // setup blocks

  // workspace carve (~32 MB)
  char* p = (char*)d_ws;
  auto carve = [&](size_t bytes)->char* { char* q = p; p += (bytes + 255) & ~(size_t)255; return q; };
  int*            deg     = (int*)     carve(sizeof(int)    * (size_t)N);
  int*            offsets = (int*)     carve(sizeof(int)    * (size_t)(N+1));
  float*          dinv    = (float*)   carve(sizeof(float)  * (size_t)N);
  int*            bsum    = (int*)     carve(sizeof(int)    * 256);
  int*            gb      = (int*)     carve(sizeof(int)    * (size_t)(G+1));
  float*          gsum    = (float*)   carve(sizeof(float)  * (size_t)G * H);
  unsigned short* csr_src = (unsigned short*)carve(sizeof(unsigned short) * ((size_t)E + 8*(size_t)N)); // 8-padded
  unsigned short* rank    = (unsigned short*)carve(sizeof(unsigned short) * (size_t)E);
  float4*         y0      = (float4*)  carve(sizeof(float4) * (size_t)(N+1));          // +1 sentinel zero row
  ushort16*       ybufA   = (ushort16*)carve(sizeof(ushort16) * (size_t)(N+1) * H);    // +1 sentinel zero row
  ushort16*       ybufB   = (ushort16*)carve(sizeof(ushort16) * (size_t)(N+1) * H);    // +1 sentinel zero row
  ushort16*       wp2     = (ushort16*)carve(sizeof(ushort16) * 16384);
  ushort16*       wp3     = (ushort16*)carve(sizeof(ushort16) * 16384);

  const int* src = ei;
  const int* dst = ei + E;

  hipLaunchKernelGGL(k_setup, dim3(SB + 16), dim3(256), 0, stream,
                     deg, gsum, batch, N, G, gb, SB, W2, W3, wp2, wp3,
                     y0, (unsigned short*)ybufA, (unsigned short*)ybufB);

  hipLaunchKernelGGL(k_count_rank, dim3((E+255)/256),   dim3(256), 0, stream, dst, E, deg, rank);
  hipLaunchKernelGGL(k_scan1,      dim3(B),             dim3(256), 0, stream, deg, N, offsets, bsum, dinv, pos, y0);
  hipLaunchKernelGGL(k_scan3b,     dim3(B),             dim3(256), 0, stream, offsets, N, bsum, B);
  hipLaunchKernelGGL(k_fill2,      dim3((E+N+255)/256), dim3(256), 0, stream, src, dst, E, N, offsets, deg, rank, csr_src);

  // layer 1 (aggregate-first 3-wide gather + fused 3->128 dense; prescale fused into scan1)
  hipLaunchKernelGGL(k_layer1,   dim3((N+255)/256), dim3(256), 0, stream, y0, offsets, csr_src, dinv, W1, b1, ybufA, N);

  // layer 2 (fused aggregate + MFMA, bf16 y out via LDS-staged coalesced store)
  hipLaunchKernelGGL(k_aggdense<0>, dim3((N+15)/16), dim3(256), 0, stream,
                     ybufA, offsets, csr_src, dinv, wp2, b2, ybufB, (const int*)nullptr, (float*)nullptr, N);

  // layer 3 (fused aggregate + MFMA + mean-pool numerator into gsum)
  hipLaunchKernelGGL(k_aggdense<1>, dim3((N+15)/16), dim3(256), 0, stream,
                     ybufB, offsets, csr_src, dinv, wp3, b3, (ushort16*)nullptr, batch, gsum, N);

  hipLaunchKernelGGL(k_head, dim3(G), dim3(64), 0, stream, gsum, gb, Wl1, bl1, Wl2, bl2, out);
}

// Round 2
// 233.610 us; speedup vs baseline: 1.0904x; 1.0253x over previous
//
#include <hip/hip_runtime.h>

#define H 128
#define CAP 64        // fixed CSR capacity per node (Poisson(16) in-deg: P(>=63) ~ 1e-17)
#define LSTRIDE 136   // LDS row stride in bf16 elems: 272B, 16B-aligned, 2-way bank (free)
#define PSTR 132      // pool stride in floats: rl*132 -> bank offset rl*4, 2-way (free)
typedef unsigned int uint32;
typedef unsigned short ushort16;
typedef __attribute__((ext_vector_type(8))) short bf16x8;
typedef __attribute__((ext_vector_type(4))) float f32x4;

static __device__ __forceinline__ ushort16 f2bf(float f){
  uint32 u = __float_as_uint(f);
  uint32 r = (u + 0x7fff + ((u >> 16) & 1)) >> 16;   // RNE bf16 (finite values)
  return (ushort16)r;
}
static __device__ __forceinline__ float bflo(uint32 u){ return __uint_as_float(u << 16); }
static __device__ __forceinline__ float bfhi(uint32 u){ return __uint_as_float(u & 0xffff0000u); }

// fused setup: deg=1 (self-loop), gsum=0, gb[0..G]; zero sentinel rows (y0[N], ybufA[N], ybufB[N]);
// csr slot array pre-baked: slot0 = self index, slots 1..63 = sentinel N;
// last 16 blocks prep W2/W3 into MFMA B-frag bf16
__global__ __launch_bounds__(256) void k_setup(int* __restrict__ deg, float* __restrict__ gsum,
                                               const int* __restrict__ batch, int n, int G,
                                               int* __restrict__ gb, int SB,
                                               const float* __restrict__ W2, const float* __restrict__ W3,
                                               ushort16* __restrict__ wp2, ushort16* __restrict__ wp3,
                                               float4* __restrict__ y0,
                                               unsigned short* __restrict__ ybA,
                                               unsigned short* __restrict__ ybB,
                                               uint4* __restrict__ csr4){
  int b = blockIdx.x;
  if (b < SB){
    int i = b*256 + threadIdx.x;
    int T = SB*256;
    // pre-bake CSR slots: (n+1)*CAP ushorts = (n+1)*8 uint4 blocks
    uint32 ss = (uint32)n | ((uint32)n << 16);
    int NB = (n+1)*8;
    for (int j = i; j < NB; j += T){
      uint4 v; v.x = ss; v.y = ss; v.z = ss; v.w = ss;
      if ((j & 7) == 0){
        int node = j >> 3;
        v.x = (uint32)((node < n)? node : n) | ((uint32)n << 16);  // slot0 = self
      }
      csr4[j] = v;
    }
    if (i < n) deg[i] = 1;                    // self-loop pre-counted
    if (i < G*H) gsum[i] = 0.f;
    if (i < H){ ybA[(size_t)n*H + i] = 0; ybB[(size_t)n*H + i] = 0; }
    if (i == 0) y0[n] = make_float4(0.f, 0.f, 0.f, 0.f);
    if (i <= G){
      int lo = 0, hi = n;
      while (lo < hi){ int m = (lo + hi) >> 1; if (batch[m] < i) lo = m + 1; else hi = m; }
      gb[i] = lo;
    }
  } else {
    int gid = (b - SB)*256 + threadIdx.x;   // 0..4095
    const float* W = (gid < 2048) ? W2 : W3;
    ushort16* wp   = (gid < 2048) ? wp2 : wp3;
    int tid = gid & 2047;
    int frag = tid >> 6, lane = tid & 63;
    int kt = frag >> 3, ct = frag & 7;
    int m = lane & 15, quad = lane >> 4;
    const float* wrow = &W[(kt*32 + quad*8)*H + ct*16 + m];
    ushort16 vals[8];
    #pragma unroll
    for (int j = 0; j < 8; j++) vals[j] = f2bf(wrow[j*H]);
    uint4 o;
    o.x = (uint32)vals[0] | ((uint32)vals[1] << 16);
    o.y = (uint32)vals[2] | ((uint32)vals[3] << 16);
    o.z = (uint32)vals[4] | ((uint32)vals[5] << 16);
    o.w = (uint32)vals[6] | ((uint32)vals[7] << 16);
    *(uint4*)&wp[(size_t)tid*8] = o;
  }
}

// one-pass CSR fill: edge e -> slot atomicAdd(deg[dst]) in dst's fixed 64-slot bucket
__global__ __launch_bounds__(256) void k_fill(const int* __restrict__ src, const int* __restrict__ dst,
                                              int E, int* __restrict__ deg,
                                              unsigned short* __restrict__ csr_src){
  int i = blockIdx.x*256 + threadIdx.x;
  if (i < E){
    int d = dst[i];
    int slot = atomicAdd(&deg[d], 1);
    if (slot < CAP) csr_src[((size_t)d << 6) + slot] = (unsigned short)src[i];
  }
}

// dinv prescale: y0[i] = rsqrt(deg[i]) * pos[i]
__global__ __launch_bounds__(256) void k_pre(const int* __restrict__ deg, const float* __restrict__ pos,
                                             float4* __restrict__ y0, int n){
  int i = blockIdx.x*256 + threadIdx.x;
  if (i < n){
    float dv = rsqrtf((float)deg[i]);
    y0[i] = make_float4(pos[3*i]*dv, pos[3*i+1]*dv, pos[3*i+2]*dv, 0.f);
  }
}

// Fused layer 1: per node, a = dinv * sum_src y0[src] (3-wide gather), then
// y1[node,c] = bf16( dinv * relu(a . W1[:,c] + b1[c]) ) for all 128 cols (W1/b1 wave-uniform).
// Fixed-capacity CSR: branchless 8-chunks, next-index prefetch.
__global__ __launch_bounds__(256) void k_layer1(const float4* __restrict__ y0, const int* __restrict__ deg,
      const unsigned short* __restrict__ csr_src,
      const float* __restrict__ W1, const float* __restrict__ b1,
      ushort16* __restrict__ y1, int n){
  int node = blockIdx.x*256 + threadIdx.x;
  if (node >= n) return;
  int cnt = deg[node];
  int lo = node << 6;
  int hi = lo + ((cnt + 7) & ~7);
  float x=0.f, y=0.f, z=0.f;
  uint4 iv = *(const uint4*)&csr_src[lo];
  for (int e = lo; e < hi; e += 8){
    uint4 ivn = *(const uint4*)&csr_src[e + 8];   // prefetch (safe: 64-slot region + pad row)
    int s0 = iv.x & 0xffff, s1 = iv.x >> 16;
    int s2 = iv.y & 0xffff, s3 = iv.y >> 16;
    int s4 = iv.z & 0xffff, s5 = iv.z >> 16;
    int s6 = iv.w & 0xffff, s7 = iv.w >> 16;
    float4 v0 = y0[s0], v1 = y0[s1], v2 = y0[s2], v3 = y0[s3];
    float4 v4 = y0[s4], v5 = y0[s5], v6 = y0[s6], v7 = y0[s7];
    x += ((v0.x+v1.x)+(v2.x+v3.x)) + ((v4.x+v5.x)+(v6.x+v7.x));
    y += ((v0.y+v1.y)+(v2.y+v3.y)) + ((v4.y+v5.y)+(v6.y+v7.y));
    z += ((v0.z+v1.z)+(v2.z+v3.z)) + ((v4.z+v5.z)+(v6.z+v7.z));
    iv = ivn;
  }
  float dn = rsqrtf((float)cnt);
  x *= dn; y *= dn; z *= dn;
  ushort16* rowp = &y1[(size_t)node*H];
  for (int c8 = 0; c8 < 16; c8++){
    float4 wa0 = *(const float4*)&W1[c8*8];
    float4 wa1 = *(const float4*)&W1[c8*8+4];
    float4 wb0 = *(const float4*)&W1[H + c8*8];
    float4 wb1 = *(const float4*)&W1[H + c8*8+4];
    float4 wc0 = *(const float4*)&W1[2*H + c8*8];
    float4 wc1 = *(const float4*)&W1[2*H + c8*8+4];
    float4 bb0 = *(const float4*)&b1[c8*8];
    float4 bb1 = *(const float4*)&b1[c8*8+4];
    float o0 = fmaxf(x*wa0.x + y*wb0.x + z*wc0.x + bb0.x, 0.f) * dn;
    float o1 = fmaxf(x*wa0.y + y*wb0.y + z*wc0.y + bb0.y, 0.f) * dn;
    float o2 = fmaxf(x*wa0.z + y*wb0.z + z*wc0.z + bb0.z, 0.f) * dn;
    float o3 = fmaxf(x*wa0.w + y*wb0.w + z*wc0.w + bb0.w, 0.f) * dn;
    float o4 = fmaxf(x*wa1.x + y*wb1.x + z*wc1.x + bb1.x, 0.f) * dn;
    float o5 = fmaxf(x*wa1.y + y*wb1.y + z*wc1.y + bb1.y, 0.f) * dn;
    float o6 = fmaxf(x*wa1.z + y*wb1.z + z*wc1.z + bb1.z, 0.f) * dn;
    float o7 = fmaxf(x*wa1.w + y*wb1.w + z*wc1.w + bb1.w, 0.f) * dn;
    uint4 o;
    o.x = (uint32)f2bf(o0) | ((uint32)f2bf(o1) << 16);
    o.y = (uint32)f2bf(o2) | ((uint32)f2bf(o3) << 16);
    o.z = (uint32)f2bf(o4) | ((uint32)f2bf(o5) << 16);
    o.w = (uint32)f2bf(o6) | ((uint32)f2bf(o7) << 16);
    *(uint4*)&rowp[c8*8] = o;
  }
}

// Fused aggregate + MFMA dense (full gather parallelism: 16 nodes/block, 16 lanes/node, one pass).
// Fixed-capacity CSR: branchless 8-chunks with one uint4 index load (prefetched) per chunk.
// POOL=0: yout tile staged in LDS then coalesced 16B/lane bf16 stores (layer 2)
// POOL=1: relu(aW+b) -> LDS tile -> parallel segmented atomicAdd into gsum (layer 3 + pool numerator)
template<int POOL>
__global__ __launch_bounds__(256) void k_aggdense(const ushort16* __restrict__ y, const int* __restrict__ deg,
      const unsigned short* __restrict__ csr_src, const ushort16* __restrict__ wp,
      const float* __restrict__ bias,
      ushort16* __restrict__ yout, const int* __restrict__ batch, float* __restrict__ gsum, int n){
  __shared__ unsigned short As[16*LSTRIDE];          // 4352 B
  __shared__ float pool[POOL ? 16*PSTR : 1];         // 8448 B (POOL only)
  __shared__ unsigned short outs[POOL ? 1 : 16*PSTR];// 4224 B (non-POOL: staged bf16 out tile)
  __shared__ int sbatch[POOL ? 16 : 1];
  __shared__ float sdinv[POOL ? 1 : 16];
  int tid = threadIdx.x;
  int node16 = blockIdx.x*16;
  int nl = tid >> 4;                 // local node 0..15
  int node = node16 + nl;
  int f8 = (tid & 15) * 8;

  if (tid < 16){
    int nn = node16 + tid;
    if (POOL) sbatch[tid] = (nn < n) ? batch[nn] : -1;
    else      sdinv[tid]  = (nn < n) ? rsqrtf((float)deg[nn]) : 0.f;
  }

  // ---- phase A: aggregate (branchless 8-wide chunks over fixed-capacity CSR) ----
  float a0=0,a1=0,a2=0,a3=0,a4=0,a5=0,a6=0,a7=0;
  float dn = 0.f;
  #define ADDU(u) { a0+=bflo(u.x); a1+=bfhi(u.x); a2+=bflo(u.y); a3+=bfhi(u.y); \
                    a4+=bflo(u.z); a5+=bfhi(u.z); a6+=bflo(u.w); a7+=bfhi(u.w); }
  if (node < n){
    int cnt = deg[node];
    int lo = node << 6;
    int hi = lo + ((cnt + 7) & ~7);
    dn = rsqrtf((float)cnt);
    uint4 iv = *(const uint4*)&csr_src[lo];
    for (int e = lo; e < hi; e += 8){
      uint4 ivn = *(const uint4*)&csr_src[e + 8];   // prefetch next chunk's indices
      int s0 = iv.x & 0xffff, s1 = iv.x >> 16;
      int s2 = iv.y & 0xffff, s3 = iv.y >> 16;
      int s4 = iv.z & 0xffff, s5 = iv.z >> 16;
      int s6 = iv.w & 0xffff, s7 = iv.w >> 16;
      uint4 u0 = *(const uint4*)&y[(size_t)s0*H + f8];
      uint4 u1 = *(const uint4*)&y[(size_t)s1*H + f8];
      uint4 u2 = *(const uint4*)&y[(size_t)s2*H + f8];
      uint4 u3 = *(const uint4*)&y[(size_t)s3*H + f8];
      uint4 u4 = *(const uint4*)&y[(size_t)s4*H + f8];
      uint4 u5 = *(const uint4*)&y[(size_t)s5*H + f8];
      uint4 u6 = *(const uint4*)&y[(size_t)s6*H + f8];
      uint4 u7 = *(const uint4*)&y[(size_t)s7*H + f8];
      ADDU(u0); ADDU(u1); ADDU(u2); ADDU(u3);
      ADDU(u4); ADDU(u5); ADDU(u6); ADDU(u7);
      iv = ivn;
    }
  }
  #undef ADDU
  uint4 o;
  o.x = (uint32)f2bf(a0*dn) | ((uint32)f2bf(a1*dn) << 16);
  o.y = (uint32)f2bf(a2*dn) | ((uint32)f2bf(a3*dn) << 16);
  o.z = (uint32)f2bf(a4*dn) | ((uint32)f2bf(a5*dn) << 16);
  o.w = (uint32)f2bf(a6*dn) | ((uint32)f2bf(a7*dn) << 16);
  *(uint4*)&As[nl*LSTRIDE + f8] = o;
  __syncthreads();

  // ---- phase B: MFMA — wave w handles col-tiles {2w, 2w+1} over the 16 staged rows ----
  int wave = tid >> 6;
  int lane = tid & 63;
  int m = lane & 15, quad = lane >> 4;
  f32x4 acc0 = {0.f,0.f,0.f,0.f}, acc1 = {0.f,0.f,0.f,0.f};
  int ct0 = wave*2, ct1 = wave*2 + 1;
  #pragma unroll
  for (int kt = 0; kt < 4; kt++){
    bf16x8 af = *(const bf16x8*)&As[m*LSTRIDE + kt*32 + quad*8];
    bf16x8 b0 = *(const bf16x8*)&wp[(size_t)((kt*8+ct0)*64 + lane)*8];
    bf16x8 b1 = *(const bf16x8*)&wp[(size_t)((kt*8+ct1)*64 + lane)*8];
    acc0 = __builtin_amdgcn_mfma_f32_16x16x32_bf16(af, b0, acc0, 0, 0, 0);
    acc1 = __builtin_amdgcn_mfma_f32_16x16x32_bf16(af, b1, acc1, 0, 0, 0);
  }
  // C/D layout: col = ct*16 + m, row (in tile) = quad*4 + r
  #pragma unroll
  for (int j = 0; j < 2; j++){
    int ct = wave*2 + j;
    int col = ct*16 + m;
    float bv = bias[col];
    f32x4 ac = j ? acc1 : acc0;
    #pragma unroll
    for (int r = 0; r < 4; r++){
      int rl = quad*4 + r;
      int orow = node16 + rl;
      if (orow < n){
        float v = fmaxf(ac[r] + bv, 0.f);
        if (POOL) pool[rl*PSTR + col] = v;                            // one lane per (row,col)
        else      outs[rl*PSTR + col] = f2bf(v * sdinv[rl]);
      }
    }
  }
  __syncthreads();
  if (POOL){
    // parallel segmented tail: 256 threads = 128 cols x 2 row-halves
    int col = tid & 127;
    int half = tid >> 7;
    float run = 0.f; int gprev = -1;
    for (int r = half*8; r < half*8 + 8; r++){
      int g = sbatch[r];
      if (g < 0) break;            // tail rows only
      if (g != gprev){
        if (gprev >= 0) atomicAdd(&gsum[gprev*H + col], run);
        run = 0.f; gprev = g;
      }
      run += pool[r*PSTR + col];
    }
    if (gprev >= 0) atomicAdd(&gsum[gprev*H + col], run);
  } else {
    // coalesced store: thread t writes row t>>4, 8 bf16 at (t&15)*8
    int row = tid >> 4;
    int orow = node16 + row;
    if (orow < n){
      const unsigned short* sp = &outs[row*PSTR + f8];
      uint4 v;
      v.x = (uint32)sp[0] | ((uint32)sp[1] << 16);
      v.y = (uint32)sp[2] | ((uint32)sp[3] << 16);
      v.z = (uint32)sp[4] | ((uint32)sp[5] << 16);
      v.w = (uint32)sp[6] | ((uint32)sp[7] << 16);
      *(uint4*)&yout[(size_t)orow*H + f8] = v;
    }
  }
}

// MLP head: relu((gsum/cnt) @ Wl1 + bl1) @ Wl2 + bl2
__global__ __launch_bounds__(64) void k_head(const float* __restrict__ gsum, const int* __restrict__ gb,
            const float* __restrict__ Wl1, const float* __restrict__ bl1,
            const float* __restrict__ Wl2, const float* __restrict__ bl2,
            float* __restrict__ out){
  int g = blockIdx.x;
  int t = threadIdx.x;
  __shared__ float gs[H];
  __shared__ float h1[64];
  float inv = 1.f / fmaxf((float)(gb[g+1] - gb[g]), 1.f);
  gs[t]      = gsum[g*H + t]      * inv;
  gs[64 + t] = gsum[g*H + 64 + t] * inv;
  __syncthreads();
  float acc = bl1[t];
  for (int k = 0; k < H; k++) acc += gs[k] * Wl1[k*64 + t];
  h1[t] = fmaxf(acc, 0.f);
  __syncthreads();
  if (t < 10){
    float o = bl2[t];
    for (int j = 0; j < 64; j++) o += h1[j] * Wl2[j*10 + t];
    out[g*10 + t] = o;
  }
}

extern "C" void kernel_launch(void* const* d_in, const int* in_sizes, int n_in,
                              void* d_out, int out_size, void* d_ws, size_t ws_size,
                              hipStream_t stream){
  const float* pos = (const float*)d_in[0];
  const int*  ei   = (const int*)d_in[1];
  const int*  batch= (const int*)d_in[2];
  const float* W1 = (const float*)d_in[3];
  const float* b1 = (const float*)d_in[4];
  const float* W2 = (const float*)d_in[5];
  const float* b2 = (const float*)d_in[6];
  const float* W3 = (const float*)d_in[7];
  const float* b3 = (const float*)d_in[8];
  const float* Wl1 = (const float*)d_in[9];
  const float* bl1 = (const float*)d_in[10];
  const float* Wl2 = (const float*)d_in[11];
  const float* bl2 = (const float*)d_in[12];
  float* out = (float*)d_out;

  int N = in_sizes[0] / 3;     // 50000 (< 65535 required for ushort CSR + sentinel)
  int E = in_sizes[1] / 2;     // 800000
  int G = out_size / 10;       // 64
  int SB = (N + 255) / 256;    // setup blocks

  // workspace carve (~34 MB)
  char* p = (char*)d_ws;
  auto carve = [&](size_t bytes)->char* { char* q = p; p += (bytes + 255) & ~(size_t)255; return q; };
  int*            deg     = (int*)     carve(sizeof(int)    * (size_t)N);
  int*            gb      = (int*)     carve(sizeof(int)    * (size_t)(G+1));
  float*          gsum    = (float*)   carve(sizeof(float)  * (size_t)G * H);
  unsigned short* csr_src = (unsigned short*)carve(sizeof(unsigned short) * (size_t)(N+1) * CAP);
  float4*         y0      = (float4*)  carve(sizeof(float4) * (size_t)(N+1));          // +1 sentinel zero row
  ushort16*       ybufA   = (ushort16*)carve(sizeof(ushort16) * (size_t)(N+1) * H);    // +1 sentinel zero row
  ushort16*       ybufB   = (ushort16*)carve(sizeof(ushort16) * (size_t)(N+1) * H);    // +1 sentinel zero row
  ushort16*       wp2     = (ushort16*)carve(sizeof(ushort16) * 16384);
  ushort16*       wp3     = (ushort16*)carve(sizeof(ushort16) * 16384);

  const int* src = ei;
  const int* dst = ei + E;

  hipLaunchKernelGGL(k_setup, dim3(SB + 16), dim3(256), 0, stream,
                     deg, gsum, batch, N, G, gb, SB, W2, W3, wp2, wp3,
                     y0, (unsigned short*)ybufA, (unsigned short*)ybufB, (uint4*)csr_src);

  // one-pass CSR fill (fixed capacity, no scan)
  hipLaunchKernelGGL(k_fill, dim3((E+255)/256), dim3(256), 0, stream, src, dst, E, deg, csr_src);

  // dinv prescale (needs final deg)
  hipLaunchKernelGGL(k_pre, dim3((N+255)/256), dim3(256), 0, stream, deg, pos, y0, N);

  // layer 1 (aggregate-first 3-wide gather + fused 3->128 dense)
  hipLaunchKernelGGL(k_layer1, dim3((N+255)/256), dim3(256), 0, stream, y0, deg, csr_src, W1, b1, ybufA, N);

  // layer 2 (fused aggregate + MFMA, bf16 y out via LDS-staged coalesced store)
  hipLaunchKernelGGL(k_aggdense<0>, dim3((N+15)/16), dim3(256), 0, stream,
                     ybufA, deg, csr_src, wp2, b2, ybufB, (const int*)nullptr, (float*)nullptr, N);

  // layer 3 (fused aggregate + MFMA + mean-pool numerator into gsum)
  hipLaunchKernelGGL(k_aggdense<1>, dim3((N+15)/16), dim3(256), 0, stream,
                     ybufB, deg, csr_src, wp3, b3, (ushort16*)nullptr, batch, gsum, N);

  hipLaunchKernelGGL(k_head, dim3(G), dim3(64), 0, stream, gsum, gb, Wl1, bl1, Wl2, bl2, out);
}

// Round 3
// 226.543 us; speedup vs baseline: 1.1244x; 1.0312x over previous
//
#include <hip/hip_runtime.h>

#define H 128
#define CAP 64        // fixed CSR capacity per node (Poisson(16) in-deg: P(>=64) ~ 1e-17)
#define LSTRIDE 136   // LDS row stride in bf16 elems: 272B, 16B-aligned, 2-way bank (free)
#define PSTR 132      // pool stride in floats: rl*132 -> bank offset rl*4, 2-way (free)
typedef unsigned int uint32;
typedef unsigned short ushort16;
typedef __attribute__((ext_vector_type(8))) short bf16x8;
typedef __attribute__((ext_vector_type(4))) float f32x4;

static __device__ __forceinline__ ushort16 f2bf(float f){
  uint32 u = __float_as_uint(f);
  uint32 r = (u + 0x7fff + ((u >> 16) & 1)) >> 16;   // RNE bf16 (finite values)
  return (ushort16)r;
}
static __device__ __forceinline__ float bflo(uint32 u){ return __uint_as_float(u << 16); }
static __device__ __forceinline__ float bfhi(uint32 u){ return __uint_as_float(u & 0xffff0000u); }

// fused setup: deg=0, gsum=0, gb[0..G]; zero sentinel rows (y0[N], ybufA[N], ybufB[N]);
// last 16 blocks prep W2/W3 into MFMA B-frag bf16. (No CSR pre-bake: tail clamp handles garbage.)
__global__ __launch_bounds__(256) void k_setup(int* __restrict__ deg, float* __restrict__ gsum,
                                               const int* __restrict__ batch, int n, int G,
                                               int* __restrict__ gb, int SB,
                                               const float* __restrict__ W2, const float* __restrict__ W3,
                                               ushort16* __restrict__ wp2, ushort16* __restrict__ wp3,
                                               float4* __restrict__ y0,
                                               unsigned short* __restrict__ ybA,
                                               unsigned short* __restrict__ ybB){
  int b = blockIdx.x;
  if (b < SB){
    int i = b*256 + threadIdx.x;
    if (i < n) deg[i] = 0;
    if (i < G*H) gsum[i] = 0.f;
    if (i < H){ ybA[(size_t)n*H + i] = 0; ybB[(size_t)n*H + i] = 0; }
    if (i == 0) y0[n] = make_float4(0.f, 0.f, 0.f, 0.f);
    if (i <= G){
      int lo = 0, hi = n;
      while (lo < hi){ int m = (lo + hi) >> 1; if (batch[m] < i) lo = m + 1; else hi = m; }
      gb[i] = lo;
    }
  } else {
    int gid = (b - SB)*256 + threadIdx.x;   // 0..4095
    const float* W = (gid < 2048) ? W2 : W3;
    ushort16* wp   = (gid < 2048) ? wp2 : wp3;
    int tid = gid & 2047;
    int frag = tid >> 6, lane = tid & 63;
    int kt = frag >> 3, ct = frag & 7;
    int m = lane & 15, quad = lane >> 4;
    const float* wrow = &W[(kt*32 + quad*8)*H + ct*16 + m];
    ushort16 vals[8];
    #pragma unroll
    for (int j = 0; j < 8; j++) vals[j] = f2bf(wrow[j*H]);
    uint4 o;
    o.x = (uint32)vals[0] | ((uint32)vals[1] << 16);
    o.y = (uint32)vals[2] | ((uint32)vals[3] << 16);
    o.z = (uint32)vals[4] | ((uint32)vals[5] << 16);
    o.w = (uint32)vals[6] | ((uint32)vals[7] << 16);
    *(uint4*)&wp[(size_t)tid*8] = o;
  }
}

// one-pass CSR fill, 4 edges/thread (int4): 4 independent atomic->store chains per thread for MLP
__global__ __launch_bounds__(256) void k_fill(const int* __restrict__ src, const int* __restrict__ dst,
                                              int E, int* __restrict__ deg,
                                              unsigned short* __restrict__ csr_src){
  int base = (blockIdx.x*256 + threadIdx.x) * 4;
  if (base + 3 < E){
    int4 d = *(const int4*)&dst[base];
    int4 s = *(const int4*)&src[base];
    int t0 = atomicAdd(&deg[d.x], 1);
    int t1 = atomicAdd(&deg[d.y], 1);
    int t2 = atomicAdd(&deg[d.z], 1);
    int t3 = atomicAdd(&deg[d.w], 1);
    if (t0 < CAP) csr_src[((size_t)d.x << 6) + t0] = (unsigned short)s.x;
    if (t1 < CAP) csr_src[((size_t)d.y << 6) + t1] = (unsigned short)s.y;
    if (t2 < CAP) csr_src[((size_t)d.z << 6) + t2] = (unsigned short)s.z;
    if (t3 < CAP) csr_src[((size_t)d.w << 6) + t3] = (unsigned short)s.w;
  } else if (base < E){
    for (int i = base; i < E; i++){
      int d = dst[i];
      int t = atomicAdd(&deg[d], 1);
      if (t < CAP) csr_src[((size_t)d << 6) + t] = (unsigned short)src[i];
    }
  }
}

// dinv prescale: y0[i] = rsqrt(deg[i]+1) * pos[i]
__global__ __launch_bounds__(256) void k_pre(const int* __restrict__ deg, const float* __restrict__ pos,
                                             float4* __restrict__ y0, int n){
  int i = blockIdx.x*256 + threadIdx.x;
  if (i < n){
    float dv = rsqrtf((float)(deg[i] + 1));
    y0[i] = make_float4(pos[3*i]*dv, pos[3*i+1]*dv, pos[3*i+2]*dv, 0.f);
  }
}

// Fused layer 1: per node, a = dinv * (y0[node] + sum_src y0[src]), then
// y1[node,c] = bf16( dinv * relu(a . W1[:,c] + b1[c]) ) for all 128 cols (W1/b1 wave-uniform).
// Self-contribution added directly; tail chunk index-clamped to sentinel n (zero row).
__global__ __launch_bounds__(256) void k_layer1(const float4* __restrict__ y0, const int* __restrict__ deg,
      const unsigned short* __restrict__ csr_src,
      const float* __restrict__ W1, const float* __restrict__ b1,
      ushort16* __restrict__ y1, int n){
  int node = blockIdx.x*256 + threadIdx.x;
  if (node >= n) return;
  int cnt = deg[node];
  int lo = node << 6;
  float4 own = y0[node];
  float x = own.x, y = own.y, z = own.z;
  int mm = cnt > CAP ? CAP : cnt;
  int nfull = mm >> 3, rem = mm & 7;
  #define GADD(s0,s1,s2,s3,s4,s5,s6,s7) { \
    float4 v0 = y0[s0], v1 = y0[s1], v2 = y0[s2], v3 = y0[s3]; \
    float4 v4 = y0[s4], v5 = y0[s5], v6 = y0[s6], v7 = y0[s7]; \
    x += ((v0.x+v1.x)+(v2.x+v3.x)) + ((v4.x+v5.x)+(v6.x+v7.x)); \
    y += ((v0.y+v1.y)+(v2.y+v3.y)) + ((v4.y+v5.y)+(v6.y+v7.y)); \
    z += ((v0.z+v1.z)+(v2.z+v3.z)) + ((v4.z+v5.z)+(v6.z+v7.z)); }
  if (rem){
    uint4 iv = *(const uint4*)&csr_src[lo + nfull*8];
    int s0 = (int)(iv.x & 0xffff);
    int s1 = (1 < rem)? (int)(iv.x >> 16)    : n;
    int s2 = (2 < rem)? (int)(iv.y & 0xffff) : n;
    int s3 = (3 < rem)? (int)(iv.y >> 16)    : n;
    int s4 = (4 < rem)? (int)(iv.z & 0xffff) : n;
    int s5 = (5 < rem)? (int)(iv.z >> 16)    : n;
    int s6 = (6 < rem)? (int)(iv.w & 0xffff) : n;
    int s7 = (7 < rem)? (int)(iv.w >> 16)    : n;
    GADD(s0,s1,s2,s3,s4,s5,s6,s7);
  }
  if (nfull){
    uint4 iv = *(const uint4*)&csr_src[lo];
    for (int c = 0; c < nfull; c++){
      uint4 nx = *(const uint4*)&csr_src[lo + c*8 + 8];  // prefetch (stays inside (N+1)*64 slots)
      int s0 = iv.x & 0xffff, s1 = iv.x >> 16;
      int s2 = iv.y & 0xffff, s3 = iv.y >> 16;
      int s4 = iv.z & 0xffff, s5 = iv.z >> 16;
      int s6 = iv.w & 0xffff, s7 = iv.w >> 16;
      GADD(s0,s1,s2,s3,s4,s5,s6,s7);
      iv = nx;
    }
  }
  #undef GADD
  float dn = rsqrtf((float)(cnt + 1));
  x *= dn; y *= dn; z *= dn;
  ushort16* rowp = &y1[(size_t)node*H];
  for (int c8 = 0; c8 < 16; c8++){
    float4 wa0 = *(const float4*)&W1[c8*8];
    float4 wa1 = *(const float4*)&W1[c8*8+4];
    float4 wb0 = *(const float4*)&W1[H + c8*8];
    float4 wb1 = *(const float4*)&W1[H + c8*8+4];
    float4 wc0 = *(const float4*)&W1[2*H + c8*8];
    float4 wc1 = *(const float4*)&W1[2*H + c8*8+4];
    float4 bb0 = *(const float4*)&b1[c8*8];
    float4 bb1 = *(const float4*)&b1[c8*8+4];
    float o0 = fmaxf(x*wa0.x + y*wb0.x + z*wc0.x + bb0.x, 0.f) * dn;
    float o1 = fmaxf(x*wa0.y + y*wb0.y + z*wc0.y + bb0.y, 0.f) * dn;
    float o2 = fmaxf(x*wa0.z + y*wb0.z + z*wc0.z + bb0.z, 0.f) * dn;
    float o3 = fmaxf(x*wa0.w + y*wb0.w + z*wc0.w + bb0.w, 0.f) * dn;
    float o4 = fmaxf(x*wa1.x + y*wb1.x + z*wc1.x + bb1.x, 0.f) * dn;
    float o5 = fmaxf(x*wa1.y + y*wb1.y + z*wc1.y + bb1.y, 0.f) * dn;
    float o6 = fmaxf(x*wa1.z + y*wb1.z + z*wc1.z + bb1.z, 0.f) * dn;
    float o7 = fmaxf(x*wa1.w + y*wb1.w + z*wc1.w + bb1.w, 0.f) * dn;
    uint4 o;
    o.x = (uint32)f2bf(o0) | ((uint32)f2bf(o1) << 16);
    o.y = (uint32)f2bf(o2) | ((uint32)f2bf(o3) << 16);
    o.z = (uint32)f2bf(o4) | ((uint32)f2bf(o5) << 16);
    o.w = (uint32)f2bf(o6) | ((uint32)f2bf(o7) << 16);
    *(uint4*)&rowp[c8*8] = o;
  }
}

// Fused aggregate + MFMA dense (full gather parallelism: 16 nodes/block, 16 lanes/node, one pass).
// Self row added directly (coalesced); tail chunk clamped to sentinel n (zero row).
// POOL=0: yout tile staged in LDS then coalesced 16B/lane bf16 stores (layer 2)
// POOL=1: relu(aW+b) -> LDS tile -> parallel segmented atomicAdd into gsum (layer 3 + pool numerator)
template<int POOL>
__global__ __launch_bounds__(256) void k_aggdense(const ushort16* __restrict__ y, const int* __restrict__ deg,
      const unsigned short* __restrict__ csr_src, const ushort16* __restrict__ wp,
      const float* __restrict__ bias,
      ushort16* __restrict__ yout, const int* __restrict__ batch, float* __restrict__ gsum, int n){
  __shared__ unsigned short As[16*LSTRIDE];          // 4352 B
  __shared__ float pool[POOL ? 16*PSTR : 1];         // 8448 B (POOL only)
  __shared__ unsigned short outs[POOL ? 1 : 16*PSTR];// 4224 B (non-POOL: staged bf16 out tile)
  __shared__ int sbatch[POOL ? 16 : 1];
  __shared__ float sdinv[POOL ? 1 : 16];
  int tid = threadIdx.x;
  int node16 = blockIdx.x*16;
  int nl = tid >> 4;                 // local node 0..15
  int node = node16 + nl;
  int f8 = (tid & 15) * 8;

  if (tid < 16){
    int nn = node16 + tid;
    if (POOL) sbatch[tid] = (nn < n) ? batch[nn] : -1;
    else      sdinv[tid]  = (nn < n) ? rsqrtf((float)(deg[nn] + 1)) : 0.f;
  }

  // ---- phase A: aggregate (self row + branchless 8-wide chunks, clamped tail first) ----
  float a0=0,a1=0,a2=0,a3=0,a4=0,a5=0,a6=0,a7=0;
  float dn = 0.f;
  #define ADDU(u) { a0+=bflo(u.x); a1+=bfhi(u.x); a2+=bflo(u.y); a3+=bfhi(u.y); \
                    a4+=bflo(u.z); a5+=bfhi(u.z); a6+=bflo(u.w); a7+=bfhi(u.w); }
  #define GATHER8(s0,s1,s2,s3,s4,s5,s6,s7) { \
    uint4 u0 = *(const uint4*)&y[(size_t)(s0)*H + f8]; \
    uint4 u1 = *(const uint4*)&y[(size_t)(s1)*H + f8]; \
    uint4 u2 = *(const uint4*)&y[(size_t)(s2)*H + f8]; \
    uint4 u3 = *(const uint4*)&y[(size_t)(s3)*H + f8]; \
    uint4 u4 = *(const uint4*)&y[(size_t)(s4)*H + f8]; \
    uint4 u5 = *(const uint4*)&y[(size_t)(s5)*H + f8]; \
    uint4 u6 = *(const uint4*)&y[(size_t)(s6)*H + f8]; \
    uint4 u7 = *(const uint4*)&y[(size_t)(s7)*H + f8]; \
    ADDU(u0); ADDU(u1); ADDU(u2); ADDU(u3); \
    ADDU(u4); ADDU(u5); ADDU(u6); ADDU(u7); }
  if (node < n){
    int cnt = deg[node];
    int lo = node << 6;
    dn = rsqrtf((float)(cnt + 1));
    uint4 uo = *(const uint4*)&y[(size_t)node*H + f8];   // self row (coalesced)
    ADDU(uo);
    int mm = cnt > CAP ? CAP : cnt;
    int nfull = mm >> 3, rem = mm & 7;
    if (rem){
      uint4 iv = *(const uint4*)&csr_src[lo + nfull*8];
      int s0 = (int)(iv.x & 0xffff);
      int s1 = (1 < rem)? (int)(iv.x >> 16)    : n;
      int s2 = (2 < rem)? (int)(iv.y & 0xffff) : n;
      int s3 = (3 < rem)? (int)(iv.y >> 16)    : n;
      int s4 = (4 < rem)? (int)(iv.z & 0xffff) : n;
      int s5 = (5 < rem)? (int)(iv.z >> 16)    : n;
      int s6 = (6 < rem)? (int)(iv.w & 0xffff) : n;
      int s7 = (7 < rem)? (int)(iv.w >> 16)    : n;
      GATHER8(s0,s1,s2,s3,s4,s5,s6,s7);
    }
    if (nfull){
      uint4 iv = *(const uint4*)&csr_src[lo];
      for (int c = 0; c < nfull; c++){
        uint4 nx = *(const uint4*)&csr_src[lo + c*8 + 8];  // prefetch next chunk's indices
        int s0 = iv.x & 0xffff, s1 = iv.x >> 16;
        int s2 = iv.y & 0xffff, s3 = iv.y >> 16;
        int s4 = iv.z & 0xffff, s5 = iv.z >> 16;
        int s6 = iv.w & 0xffff, s7 = iv.w >> 16;
        GATHER8(s0,s1,s2,s3,s4,s5,s6,s7);
        iv = nx;
      }
    }
  }
  #undef GATHER8
  #undef ADDU
  uint4 o;
  o.x = (uint32)f2bf(a0*dn) | ((uint32)f2bf(a1*dn) << 16);
  o.y = (uint32)f2bf(a2*dn) | ((uint32)f2bf(a3*dn) << 16);
  o.z = (uint32)f2bf(a4*dn) | ((uint32)f2bf(a5*dn) << 16);
  o.w = (uint32)f2bf(a6*dn) | ((uint32)f2bf(a7*dn) << 16);
  *(uint4*)&As[nl*LSTRIDE + f8] = o;
  __syncthreads();

  // ---- phase B: MFMA — wave w handles col-tiles {2w, 2w+1} over the 16 staged rows ----
  int wave = tid >> 6;
  int lane = tid & 63;
  int m = lane & 15, quad = lane >> 4;
  f32x4 acc0 = {0.f,0.f,0.f,0.f}, acc1 = {0.f,0.f,0.f,0.f};
  int ct0 = wave*2, ct1 = wave*2 + 1;
  #pragma unroll
  for (int kt = 0; kt < 4; kt++){
    bf16x8 af = *(const bf16x8*)&As[m*LSTRIDE + kt*32 + quad*8];
    bf16x8 b0 = *(const bf16x8*)&wp[(size_t)((kt*8+ct0)*64 + lane)*8];
    bf16x8 b1 = *(const bf16x8*)&wp[(size_t)((kt*8+ct1)*64 + lane)*8];
    acc0 = __builtin_amdgcn_mfma_f32_16x16x32_bf16(af, b0, acc0, 0, 0, 0);
    acc1 = __builtin_amdgcn_mfma_f32_16x16x32_bf16(af, b1, acc1, 0, 0, 0);
  }
  // C/D layout: col = ct*16 + m, row (in tile) = quad*4 + r
  #pragma unroll
  for (int j = 0; j < 2; j++){
    int ct = wave*2 + j;
    int col = ct*16 + m;
    float bv = bias[col];
    f32x4 ac = j ? acc1 : acc0;
    #pragma unroll
    for (int r = 0; r < 4; r++){
      int rl = quad*4 + r;
      int orow = node16 + rl;
      if (orow < n){
        float v = fmaxf(ac[r] + bv, 0.f);
        if (POOL) pool[rl*PSTR + col] = v;                            // one lane per (row,col)
        else      outs[rl*PSTR + col] = f2bf(v * sdinv[rl]);
      }
    }
  }
  __syncthreads();
  if (POOL){
    // parallel segmented tail: 256 threads = 128 cols x 2 row-halves
    int col = tid & 127;
    int half = tid >> 7;
    float run = 0.f; int gprev = -1;
    for (int r = half*8; r < half*8 + 8; r++){
      int g = sbatch[r];
      if (g < 0) break;            // tail rows only
      if (g != gprev){
        if (gprev >= 0) atomicAdd(&gsum[gprev*H + col], run);
        run = 0.f; gprev = g;
      }
      run += pool[r*PSTR + col];
    }
    if (gprev >= 0) atomicAdd(&gsum[gprev*H + col], run);
  } else {
    // coalesced store: thread t writes row t>>4, 8 bf16 at (t&15)*8
    int row = tid >> 4;
    int orow = node16 + row;
    if (orow < n){
      const unsigned short* sp = &outs[row*PSTR + f8];
      uint4 v;
      v.x = (uint32)sp[0] | ((uint32)sp[1] << 16);
      v.y = (uint32)sp[2] | ((uint32)sp[3] << 16);
      v.z = (uint32)sp[4] | ((uint32)sp[5] << 16);
      v.w = (uint32)sp[6] | ((uint32)sp[7] << 16);
      *(uint4*)&yout[(size_t)orow*H + f8] = v;
    }
  }
}

// MLP head: relu((gsum/cnt) @ Wl1 + bl1) @ Wl2 + bl2
__global__ __launch_bounds__(64) void k_head(const float* __restrict__ gsum, const int* __restrict__ gb,
            const float* __restrict__ Wl1, const float* __restrict__ bl1,
            const float* __restrict__ Wl2, const float* __restrict__ bl2,
            float* __restrict__ out){
  int g = blockIdx.x;
  int t = threadIdx.x;
  __shared__ float gs[H];
  __shared__ float h1[64];
  float inv = 1.f / fmaxf((float)(gb[g+1] - gb[g]), 1.f);
  gs[t]      = gsum[g*H + t]      * inv;
  gs[64 + t] = gsum[g*H + 64 + t] * inv;
  __syncthreads();
  float acc = bl1[t];
  for (int k = 0; k < H; k++) acc += gs[k] * Wl1[k*64 + t];
  h1[t] = fmaxf(acc, 0.f);
  __syncthreads();
  if (t < 10){
    float o = bl2[t];
    for (int j = 0; j < 64; j++) o += h1[j] * Wl2[j*10 + t];
    out[g*10 + t] = o;
  }
}

extern "C" void kernel_launch(void* const* d_in, const int* in_sizes, int n_in,
                              void* d_out, int out_size, void* d_ws, size_t ws_size,
                              hipStream_t stream){
  const float* pos = (const float*)d_in[0];
  const int*  ei   = (const int*)d_in[1];
  const int*  batch= (const int*)d_in[2];
  const float* W1 = (const float*)d_in[3];
  const float* b1 = (const float*)d_in[4];
  const float* W2 = (const float*)d_in[5];
  const float* b2 = (const float*)d_in[6];
  const float* W3 = (const float*)d_in[7];
  const float* b3 = (const float*)d_in[8];
  const float* Wl1 = (const float*)d_in[9];
  const float* bl1 = (const float*)d_in[10];
  const float* Wl2 = (const float*)d_in[11];
  const float* bl2 = (const float*)d_in[12];
  float* out = (float*)d_out;

  int N = in_sizes[0] / 3;     // 50000 (< 65535 required for ushort CSR + sentinel)
  int E = in_sizes[1] / 2;     // 800000
  int G = out_size / 10;       // 64
  int SB = (N + 255) / 256;    // setup blocks

  // workspace carve (~34 MB)
  char* p = (char*)d_ws;
  auto carve = [&](size_t bytes)->char* { char* q = p; p += (bytes + 255) & ~(size_t)255; return q; };
  int*            deg     = (int*)     carve(sizeof(int)    * (size_t)N);
  int*            gb      = (int*)     carve(sizeof(int)    * (size_t)(G+1));
  float*          gsum    = (float*)   carve(sizeof(float)  * (size_t)G * H);
  unsigned short* csr_src = (unsigned short*)carve(sizeof(unsigned short) * (size_t)(N+1) * CAP);
  float4*         y0      = (float4*)  carve(sizeof(float4) * (size_t)(N+1));          // +1 sentinel zero row
  ushort16*       ybufA   = (ushort16*)carve(sizeof(ushort16) * (size_t)(N+1) * H);    // +1 sentinel zero row
  ushort16*       ybufB   = (ushort16*)carve(sizeof(ushort16) * (size_t)(N+1) * H);    // +1 sentinel zero row
  ushort16*       wp2     = (ushort16*)carve(sizeof(ushort16) * 16384);
  ushort16*       wp3     = (ushort16*)carve(sizeof(ushort16) * 16384);

  const int* src = ei;
  const int* dst = ei + E;

  hipLaunchKernelGGL(k_setup, dim3(SB + 16), dim3(256), 0, stream,
                     deg, gsum, batch, N, G, gb, SB, W2, W3, wp2, wp3,
                     y0, (unsigned short*)ybufA, (unsigned short*)ybufB);

  // one-pass CSR fill (fixed capacity, 4 edges/thread)
  hipLaunchKernelGGL(k_fill, dim3(((E+3)/4 + 255)/256), dim3(256), 0, stream, src, dst, E, deg, csr_src);

  // dinv prescale (needs final deg)
  hipLaunchKernelGGL(k_pre, dim3((N+255)/256), dim3(256), 0, stream, deg, pos, y0, N);

  // layer 1 (aggregate-first 3-wide gather + fused 3->128 dense)
  hipLaunchKernelGGL(k_layer1, dim3((N+255)/256), dim3(256), 0, stream, y0, deg, csr_src, W1, b1, ybufA, N);

  // layer 2 (fused aggregate + MFMA, bf16 y out via LDS-staged coalesced store)
  hipLaunchKernelGGL(k_aggdense<0>, dim3((N+15)/16), dim3(256), 0, stream,
                     ybufA, deg, csr_src, wp2, b2, ybufB, (const int*)nullptr, (float*)nullptr, N);

  // layer 3 (fused aggregate + MFMA + mean-pool numerator into gsum)
  hipLaunchKernelGGL(k_aggdense<1>, dim3((N+15)/16), dim3(256), 0, stream,
                     ybufB, deg, csr_src, wp3, b3, (ushort16*)nullptr, batch, gsum, N);

  hipLaunchKernelGGL(k_head, dim3(G), dim3(64), 0, stream, gsum, gb, Wl1, bl1, Wl2, bl2, out);
}